// Round 1
// baseline (84.203 us; speedup 1.0000x reference)
//
#include <hip/hip_runtime.h>
#include <hip/hip_bf16.h>
#include <climits>

#define D_DIM 256
#define K_NN 4
#define NUM_PHONES 64
#define BIG_F 1e30f

// ---------- prep kernels: compact base survivors into phone-sorted buckets ----------

__global__ void hist_kernel(const int* __restrict__ proto_phones,
                            const int* __restrict__ proto_genders,
                            const int* __restrict__ proto_speakers,
                            const int* __restrict__ tg, const int* __restrict__ ts,
                            int* __restrict__ cnt, int N) {
    int i = blockIdx.x * blockDim.x + threadIdx.x;
    if (i < N && proto_genders[i] == tg[0] && proto_speakers[i] == ts[0]) {
        atomicAdd(&cnt[proto_phones[i]], 1);
    }
}

__global__ void scan_kernel(const int* __restrict__ cnt,
                            int* __restrict__ off, int* __restrict__ cursor) {
    if (threadIdx.x == 0) {
        int acc = 0;
        for (int p = 0; p < NUM_PHONES; ++p) { off[p] = acc; cursor[p] = acc; acc += cnt[p]; }
        off[NUM_PHONES] = acc;
    }
}

__global__ void scatter_kernel(const int* __restrict__ proto_phones,
                               const int* __restrict__ proto_genders,
                               const int* __restrict__ proto_speakers,
                               const int* __restrict__ tg, const int* __restrict__ ts,
                               int* __restrict__ cursor, int* __restrict__ list, int N) {
    int i = blockIdx.x * blockDim.x + threadIdx.x;
    if (i < N && proto_genders[i] == tg[0] && proto_speakers[i] == ts[0]) {
        int pos = atomicAdd(&cursor[proto_phones[i]], 1);
        list[pos] = i;  // order within a phone bucket is nondeterministic, but
                        // selection tie-breaks on ORIGINAL index -> output deterministic
    }
}

// ---------- main kernel: 1 block per frame, 4 waves, wave-per-candidate ----------

__device__ __forceinline__ bool lex_less(double nd, int ni, double od, int oi) {
    return (nd < od) || (nd == od && ni < oi);
}

__global__ __launch_bounds__(256)
void knn_kernel(const float* __restrict__ h,
                const float* __restrict__ protos,
                const int* __restrict__ phones,
                const int* __restrict__ off,
                const int* __restrict__ list,
                float* __restrict__ out) {
    const int t    = blockIdx.x;
    const int tid  = threadIdx.x;
    const int wave = tid >> 6;
    const int lane = tid & 63;

    const int ph = phones[t];
    const int s0 = off[ph], s1 = off[ph + 1];
    const int M  = off[NUM_PHONES];
    int segStart, segEnd;
    if (s1 - s0 >= K_NN) { segStart = s0; segEnd = s1; }   // phone-constrained
    else                 { segStart = 0;  segEnd = M;  }   // fallback to base

    // each lane owns 4 consecutive dims of h[t] (float4), reused for all candidates
    const float4 hv = reinterpret_cast<const float4*>(h + (size_t)t * D_DIM)[lane];

    // per-wave running top-4, uniform across lanes; (d2 - ||h||^2, orig idx)
    double bd[K_NN] = {BIG_F, BIG_F, BIG_F, BIG_F};
    int    bi[K_NN] = {INT_MAX, INT_MAX, INT_MAX, INT_MAX};

    for (int j = segStart + wave; j < segEnd; j += 4) {
        const int n = list[j];  // wave-uniform
        const float4 pv = reinterpret_cast<const float4*>(protos + (size_t)n * D_DIM)[lane];
        // sum_d p*(p - 2h)  ==  ||p||^2 - 2 h.p   (||h||^2 dropped: shift-invariant)
        double s = (double)pv.x * (pv.x - 2.0f * hv.x)
                 + (double)pv.y * (pv.y - 2.0f * hv.y)
                 + (double)pv.z * (pv.z - 2.0f * hv.z)
                 + (double)pv.w * (pv.w - 2.0f * hv.w);
        #pragma unroll
        for (int m = 1; m < 64; m <<= 1) s += __shfl_xor(s, m);
        // uniform insert into sorted top-4 (ascending, lexicographic on (d2, idx))
        if (lex_less(s, n, bd[K_NN - 1], bi[K_NN - 1])) {
            bd[K_NN - 1] = s; bi[K_NN - 1] = n;
            #pragma unroll
            for (int k = K_NN - 1; k > 0; --k) {
                if (lex_less(bd[k], bi[k], bd[k - 1], bi[k - 1])) {
                    double td = bd[k]; bd[k] = bd[k - 1]; bd[k - 1] = td;
                    int    ti = bi[k]; bi[k] = bi[k - 1]; bi[k - 1] = ti;
                }
            }
        }
    }

    __shared__ double sd[16];
    __shared__ int    si[16];
    __shared__ float  sw[K_NN];
    __shared__ int    sid[K_NN];

    if (lane == 0) {
        #pragma unroll
        for (int k = 0; k < K_NN; ++k) { sd[wave * 4 + k] = bd[k]; si[wave * 4 + k] = bi[k]; }
    }
    __syncthreads();

    if (tid == 0) {
        double fd[K_NN] = {BIG_F, BIG_F, BIG_F, BIG_F};
        int    fi[K_NN] = {INT_MAX, INT_MAX, INT_MAX, INT_MAX};
        for (int e = 0; e < 16; ++e) {
            double nd = sd[e]; int ni = si[e];
            if (lex_less(nd, ni, fd[K_NN - 1], fi[K_NN - 1])) {
                fd[K_NN - 1] = nd; fi[K_NN - 1] = ni;
                #pragma unroll
                for (int k = K_NN - 1; k > 0; --k) {
                    if (lex_less(fd[k], fi[k], fd[k - 1], fi[k - 1])) {
                        double td = fd[k]; fd[k] = fd[k - 1]; fd[k - 1] = td;
                        int    ti = fi[k]; fi[k] = fi[k - 1]; fi[k - 1] = ti;
                    }
                }
            }
        }
        // softmax over -d2 (TEMP=1): w_k = exp(d_min - d_k); exp(d_min - BIG) -> 0
        const double m0 = fd[0];
        float w[K_NN]; float wsum = 0.f;
        #pragma unroll
        for (int k = 0; k < K_NN; ++k) {
            float wv = (fi[k] == INT_MAX) ? 0.f : expf((float)(m0 - fd[k]));
            w[k] = wv; wsum += wv;
        }
        if (wsum <= 0.f) {  // degenerate M==0 case: reference picks protos 0..3 uniformly
            #pragma unroll
            for (int k = 0; k < K_NN; ++k) { w[k] = 0.25f; fi[k] = k; }
            wsum = 1.f;
        }
        const float inv = 1.f / wsum;
        #pragma unroll
        for (int k = 0; k < K_NN; ++k) {
            sw[k]  = w[k] * inv;
            sid[k] = (fi[k] == INT_MAX) ? 0 : fi[k];
        }
    }
    __syncthreads();

    // weighted gather: thread d handles out[t][d]
    float acc = 0.f;
    #pragma unroll
    for (int k = 0; k < K_NN; ++k)
        acc = fmaf(sw[k], protos[(size_t)sid[k] * D_DIM + tid], acc);
    out[(size_t)t * D_DIM + tid] = acc;
}

// ---------- launch ----------

extern "C" void kernel_launch(void* const* d_in, const int* in_sizes, int n_in,
                              void* d_out, int out_size, void* d_ws, size_t ws_size,
                              hipStream_t stream) {
    const float* h_clean        = (const float*)d_in[0];
    const float* prototypes     = (const float*)d_in[1];
    const int*   phones         = (const int*)d_in[2];
    const int*   proto_phones   = (const int*)d_in[3];
    const int*   proto_genders  = (const int*)d_in[4];
    const int*   proto_speakers = (const int*)d_in[5];
    const int*   tg             = (const int*)d_in[6];
    const int*   ts             = (const int*)d_in[7];
    float*       out            = (float*)d_out;

    const int T = in_sizes[2];   // 1024
    const int N = in_sizes[3];   // 100000

    // workspace layout (ints): cnt[64] | off[65] | cursor[64] | pad | list[N]
    int* cnt    = (int*)d_ws;
    int* off    = cnt + 64;
    int* cursor = off + 65;
    int* list   = (int*)d_ws + 256;

    hipMemsetAsync(cnt, 0, NUM_PHONES * sizeof(int), stream);

    const int pb = (N + 255) / 256;
    hist_kernel   <<<pb, 256, 0, stream>>>(proto_phones, proto_genders, proto_speakers, tg, ts, cnt, N);
    scan_kernel   <<<1, 64, 0, stream>>>(cnt, off, cursor);
    scatter_kernel<<<pb, 256, 0, stream>>>(proto_phones, proto_genders, proto_speakers, tg, ts, cursor, list, N);
    knn_kernel    <<<T, 256, 0, stream>>>(h_clean, prototypes, phones, off, list, out);
}

// Round 2
// 61.580 us; speedup vs baseline: 1.3674x; 1.3674x over previous
//
#include <hip/hip_runtime.h>
#include <hip/hip_bf16.h>
#include <climits>

#define D_DIM 256
#define K_NN 4
#define NUM_PHONES 64
#define SEGS 4           // N-range segments per phone bucket (parallelism in build)
#define BIG_F 1e30f

// ---------------- kernel 1: build phone-bucketed survivor lists ----------------
// Grid: (NUM_PHONES+1) * SEGS blocks. Block (p,s): scan N-range segment s, collect
// indices i with base(i) && (p==64 || phone[i]==p) into list[p*N + r0 + pos].
// p==64 is the "base" fallback list (all survivors regardless of phone).
// No pre-zeroed global state needed: cursor lives in LDS, count written at end.
// Within-segment order is nondeterministic (LDS atomic), but selection later
// tie-breaks on ORIGINAL prototype index -> output fully deterministic.

__global__ __launch_bounds__(512)
void build_lists(const int* __restrict__ proto_phones,
                 const int* __restrict__ proto_genders,
                 const int* __restrict__ proto_speakers,
                 const int* __restrict__ tg, const int* __restrict__ ts,
                 int* __restrict__ cnt2, int* __restrict__ list, int N) {
    const int b = blockIdx.x;
    const int p = b / SEGS;            // 0..63 = phone bucket, 64 = base list
    const int s = b % SEGS;
    const int r0 = (int)(((long long)s       * N) / SEGS);
    const int r1 = (int)(((long long)(s + 1) * N) / SEGS);
    const int G = tg[0], SP = ts[0];

    __shared__ int cur;
    if (threadIdx.x == 0) cur = 0;
    __syncthreads();

    int* seg = list + (size_t)p * N + r0;
    for (int i = r0 + threadIdx.x; i < r1; i += 512) {
        bool ok = (proto_genders[i] == G) & (proto_speakers[i] == SP);
        if (p < NUM_PHONES) ok = ok & (proto_phones[i] == p);
        if (ok) seg[atomicAdd(&cur, 1)] = i;
    }
    __syncthreads();
    if (threadIdx.x == 0) cnt2[b] = cur;
}

// ---------------- kernel 2: per-frame kNN + softmax + weighted gather ----------------

__device__ __forceinline__ bool lex_less(double nd, int ni, double od, int oi) {
    return (nd < od) || (nd == od && ni < oi);
}

__device__ __forceinline__ void ins4(double s, int n, double* bd, int* bi) {
    if (lex_less(s, n, bd[K_NN - 1], bi[K_NN - 1])) {
        bd[K_NN - 1] = s; bi[K_NN - 1] = n;
        #pragma unroll
        for (int k = K_NN - 1; k > 0; --k) {
            if (lex_less(bd[k], bi[k], bd[k - 1], bi[k - 1])) {
                double td = bd[k]; bd[k] = bd[k - 1]; bd[k - 1] = td;
                int    ti = bi[k]; bi[k] = bi[k - 1]; bi[k - 1] = ti;
            }
        }
    }
}

__global__ __launch_bounds__(512)
void knn_kernel(const float* __restrict__ h,
                const float* __restrict__ protos,
                const int* __restrict__ phones,
                const int* __restrict__ cnt2,
                const int* __restrict__ list,
                float* __restrict__ out, int N) {
    const int t    = blockIdx.x;
    const int tid  = threadIdx.x;
    const int wave = tid >> 6;     // 0..7
    const int lane = tid & 63;

    const int ph = phones[t];
    int bucket_cnt = 0, base_cnt = 0;
    #pragma unroll
    for (int s = 0; s < SEGS; ++s) {
        bucket_cnt += cnt2[ph * SEGS + s];
        base_cnt   += cnt2[NUM_PHONES * SEGS + s];
    }
    const int use_p = (bucket_cnt >= K_NN) ? ph : NUM_PHONES;

    // each lane owns 4 consecutive dims of h[t] (float4), reused for all candidates
    const float4 hv = reinterpret_cast<const float4*>(h + (size_t)t * D_DIM)[lane];

    // per-wave running top-4 (wave-uniform after butterfly); value = ||p||^2 - 2 h.p
    double bd[K_NN] = {BIG_F, BIG_F, BIG_F, BIG_F};
    int    bi[K_NN] = {INT_MAX, INT_MAX, INT_MAX, INT_MAX};

    for (int s = 0; s < SEGS; ++s) {
        const int r0 = (int)(((long long)s * N) / SEGS);
        const int* seg = list + (size_t)use_p * N + r0;
        const int c = cnt2[use_p * SEGS + s];
        int j = wave;
        // 2-deep unroll: overlap the two dependent load->reduce chains
        for (; j + 8 < c; j += 16) {
            const int n0 = seg[j], n1 = seg[j + 8];
            const float4 a0 = reinterpret_cast<const float4*>(protos + (size_t)n0 * D_DIM)[lane];
            const float4 a1 = reinterpret_cast<const float4*>(protos + (size_t)n1 * D_DIM)[lane];
            double s0 = (double)a0.x * (a0.x - 2.0f * hv.x)
                      + (double)a0.y * (a0.y - 2.0f * hv.y)
                      + (double)a0.z * (a0.z - 2.0f * hv.z)
                      + (double)a0.w * (a0.w - 2.0f * hv.w);
            double s1 = (double)a1.x * (a1.x - 2.0f * hv.x)
                      + (double)a1.y * (a1.y - 2.0f * hv.y)
                      + (double)a1.z * (a1.z - 2.0f * hv.z)
                      + (double)a1.w * (a1.w - 2.0f * hv.w);
            #pragma unroll
            for (int m = 1; m < 64; m <<= 1) {
                s0 += __shfl_xor(s0, m);
                s1 += __shfl_xor(s1, m);
            }
            ins4(s0, n0, bd, bi);
            ins4(s1, n1, bd, bi);
        }
        if (j < c) {
            const int n0 = seg[j];
            const float4 a0 = reinterpret_cast<const float4*>(protos + (size_t)n0 * D_DIM)[lane];
            double s0 = (double)a0.x * (a0.x - 2.0f * hv.x)
                      + (double)a0.y * (a0.y - 2.0f * hv.y)
                      + (double)a0.z * (a0.z - 2.0f * hv.z)
                      + (double)a0.w * (a0.w - 2.0f * hv.w);
            #pragma unroll
            for (int m = 1; m < 64; m <<= 1) s0 += __shfl_xor(s0, m);
            ins4(s0, n0, bd, bi);
        }
    }

    __shared__ double sd[32];
    __shared__ int    si[32];
    __shared__ float  sw[K_NN];
    __shared__ int    sid[K_NN];

    if (lane == 0) {
        #pragma unroll
        for (int k = 0; k < K_NN; ++k) { sd[wave * 4 + k] = bd[k]; si[wave * 4 + k] = bi[k]; }
    }
    __syncthreads();

    if (tid == 0) {
        double fd[K_NN] = {BIG_F, BIG_F, BIG_F, BIG_F};
        int    fi[K_NN] = {INT_MAX, INT_MAX, INT_MAX, INT_MAX};
        for (int e = 0; e < 32; ++e) ins4(sd[e], si[e], fd, fi);
        // softmax over -d2 (TEMP=1): w_k = exp(d_min - d_k); empty slots -> weight 0
        const double m0 = fd[0];
        float w[K_NN]; float wsum = 0.f;
        #pragma unroll
        for (int k = 0; k < K_NN; ++k) {
            float wv = (fi[k] == INT_MAX) ? 0.f : expf((float)(m0 - fd[k]));
            w[k] = wv; wsum += wv;
        }
        if (wsum <= 0.f) {  // degenerate M==0: reference -> protos 0..3, uniform 0.25
            #pragma unroll
            for (int k = 0; k < K_NN; ++k) { w[k] = 0.25f; fi[k] = k; }
            wsum = 1.f;
        }
        const float inv = 1.f / wsum;
        #pragma unroll
        for (int k = 0; k < K_NN; ++k) {
            sw[k]  = w[k] * inv;
            sid[k] = (fi[k] == INT_MAX) ? 0 : fi[k];
        }
    }
    __syncthreads();

    // weighted gather: thread d (< D_DIM) handles out[t][d]
    if (tid < D_DIM) {
        float acc = 0.f;
        #pragma unroll
        for (int k = 0; k < K_NN; ++k)
            acc = fmaf(sw[k], protos[(size_t)sid[k] * D_DIM + tid], acc);
        out[(size_t)t * D_DIM + tid] = acc;
    }
}

// ---------------- launch ----------------

extern "C" void kernel_launch(void* const* d_in, const int* in_sizes, int n_in,
                              void* d_out, int out_size, void* d_ws, size_t ws_size,
                              hipStream_t stream) {
    const float* h_clean        = (const float*)d_in[0];
    const float* prototypes     = (const float*)d_in[1];
    const int*   phones         = (const int*)d_in[2];
    const int*   proto_phones   = (const int*)d_in[3];
    const int*   proto_genders  = (const int*)d_in[4];
    const int*   proto_speakers = (const int*)d_in[5];
    const int*   tg             = (const int*)d_in[6];
    const int*   ts             = (const int*)d_in[7];
    float*       out            = (float*)d_out;

    const int T = in_sizes[2];   // 1024
    const int N = in_sizes[3];   // 100000

    // ws layout (ints): cnt2[(NUM_PHONES+1)*SEGS] | pad to 1024 | list[(NUM_PHONES+1)*N]
    int* cnt2 = (int*)d_ws;
    int* list = (int*)d_ws + 1024;

    build_lists<<<(NUM_PHONES + 1) * SEGS, 512, 0, stream>>>(
        proto_phones, proto_genders, proto_speakers, tg, ts, cnt2, list, N);
    knn_kernel<<<T, 512, 0, stream>>>(h_clean, prototypes, phones, cnt2, list, out, N);
}